// Round 14
// baseline (3463.638 us; speedup 1.0000x reference)
//
#include <hip/hip_runtime.h>

static constexpr int T_STEPS = 512;
static constexpr int BATCH   = 64;
static constexpr int DIN     = 256;
static constexpr int HID     = 512;
static constexpr int KDIM    = DIN + HID;   // 768
static constexpr int S4      = 193;         // LDS row stride in float4 (192 data + 1 pad)
static constexpr int NBLK    = 256;
static constexpr int NPROD   = 64;          // producers (kslices) per bgroup

__device__ __forceinline__ float fast_sigmoid(float v) {
    return 1.0f / (1.0f + __expf(-v));
}
__device__ __forceinline__ float fast_tanh(float v) {
    return 1.0f - 2.0f / (__expf(2.0f * v) + 1.0f);
}

// Relaxed agent-scope ops: L1+L2 bypass, served at the device coherence
// point. No buffer_wbl2 / buffer_inv anywhere.
__device__ __forceinline__ void store_bypass(float* p, float v) {
    __hip_atomic_store((unsigned int*)p, __float_as_uint(v),
                       __ATOMIC_RELAXED, __HIP_MEMORY_SCOPE_AGENT);
}
__device__ __forceinline__ void store_flag(unsigned* p, unsigned v) {
    __hip_atomic_store(p, v, __ATOMIC_RELAXED, __HIP_MEMORY_SCOPE_AGENT);
}
__device__ __forceinline__ unsigned load_flag(const unsigned* p) {
    return __hip_atomic_load(p, __ATOMIC_RELAXED, __HIP_MEMORY_SCOPE_AGENT);
}

// DPP-rotate add (verified R12): 0xB1 xor1, 0x4E xor2, 0x124 row_ror:4,
// 0x128 row_ror:8 -> 16-lane row sum everywhere; 0x142 row_bcast15 ->
// lanes 16-31 hold sum(0..31). bound_ctrl=1.
#define DPP_ADD(v, ctrl)                                                  \
    (v) += __uint_as_float(__builtin_amdgcn_update_dpp(                   \
        0u, __float_as_uint(v), (ctrl), 0xF, 0xF, true))

// ROUND 7:  per-producer flags + wave-wide __all poll; x-GEMM above wait.
// ROUND 8-11 (dead end): W-in-registers spills (128-VGPR allocator pin).
// ROUND 12: E-reduce ds_swizzle -> VALU DPP: 3555 -> 2766us.
// ROUND 13: retile -> 8x4/KQ32: conflicts 2.08e8 -> 2.1e6; LDS READ COUNT
//           is the binding resource, not conflicts.
// ROUND 14 (dead end): 8x8/KQ64: AGPR-shuttled acc + sched_barrier = +23%.
// ROUND 15 (neutral): local-work shuffling can't hide the inter-WG chain.
// ROUND 16: unit-major W rows fuse the cell update into the GEMM half-
//           waves (gates LDS + barrier + F serialization gone; conflicts
//           -> 0). BUT scattered owner h-publish => WRITE_SIZE 135->332MB.
// ROUND 17/18: TRANSPOSED h ping-pong h_T[k][b] in the out-tail: coalesced
//           publish (8 consecutive dwords/half-wave), dwordx4 gather (one
//           vmcnt), out[] store off the inter-WG chain, end-of-kernel
//           [b][k] fixup. R18 fixed asm modifier order (offset before sc).
// ROUND 19: R18 FAILED CORRECTNESS (absmax 5.3e-2, values up to 468).
//           Bug 1 (the killer): the [b][k] fixup raced OTHER bgroups —
//           bgroups sync only within themselves, and a fast bgroup's
//           fixup rows alias h_T[k<128][*], i.e. live ping-pong columns
//           of slower bgroups (cx fixup wrote unbounded c values into
//           what others still read as h_511^T -> the 468s). FIX: device-
//           wide wait (waves 0-3 each __all-poll one bgroup's 64 flags
//           for >=513; every WG publishes 513 before exiting its loop and
//           all 256 WGs are co-resident -> no deadlock) BEFORE the fixup.
//           Bug 2 (latent UB): gather asm outputs lacked early-clobber;
//           an output quad may alias the address pair. FIX: "=&v".
__global__ __launch_bounds__(512, 1)
void lstm_persistent(const float* __restrict__ x,
                     const float* __restrict__ Wf, const float* __restrict__ bfp,
                     const float* __restrict__ Wi, const float* __restrict__ bip,
                     const float* __restrict__ Wg, const float* __restrict__ bgp,
                     const float* __restrict__ Wo, const float* __restrict__ bop,
                     float* __restrict__ out, unsigned* __restrict__ flag_ws) {
    __shared__ float4 W4[32 * S4];        // 32 rows x 768 fp32 (UNIT-MAJOR rows)
    __shared__ float4 C4[16 * S4];        // combined [x|h] for 16 b
    __shared__ float  bias_s[32];         // unit-major: bias_s[u*4+g]

    const int tid = threadIdx.x;
    const int wg  = blockIdx.x;
    const int bgroup = (wg & 7) >> 1;                  // 0..3 (XCD-paired)
    const int kslice = ((wg >> 3) << 1) | (wg & 1);    // 0..63
    const int bg0 = bgroup * 16;
    const int k0  = kslice * 8;

    unsigned* const flags = flag_ws + bgroup * NPROD;

    // ---- one-time: stage 32 weight rows UNIT-MAJOR (r = unit*4+gate) ----
    {
        const int r    = tid >> 4;     // 0..31
        const int c0   = tid & 15;
        const int gate = r & 3;
        const int unit = k0 + (r >> 2);
        const float* wsrc = (gate == 0) ? Wf : (gate == 1) ? Wi : (gate == 2) ? Wg : Wo;
        const float4* src4 = (const float4*)(wsrc + (size_t)unit * KDIM);
        #pragma unroll 2
        for (int m = 0; m < 12; ++m)
            W4[r * S4 + c0 + 16 * m] = src4[c0 + 16 * m];
        if (tid < 32) {
            const int g2 = tid & 3;
            const float* bsrc = (g2 == 0) ? bfp : (g2 == 1) ? bip : (g2 == 2) ? bgp : bop;
            bias_s[tid] = bsrc[k0 + (tid >> 2)];
        }
    }

    // ---- one-time: stage x_0 (in-loop staging happens post-D) ----
    {
        const float4* xs = (const float4*)(x + (size_t)bg0 * DIN);
        #pragma unroll
        for (int m = 0; m < 2; ++m) {
            const int i4 = tid + 512 * m;               // 16b x 64 f4
            C4[(i4 >> 6) * S4 + (i4 & 63)] = xs[i4];
        }
    }

    // Ping-pong h buffers live in the out tail, TRANSPOSED: h_T[k][b],
    // addr = k*64 + b. Overwritten with correct [b][k] hx/cx at the end,
    // only after a DEVICE-WIDE flag wait (all 4 bgroups done).
    float* const hx_sec = out + (size_t)T_STEPS * BATCH * HID;  // buf0
    float* const cx_sec = hx_sec + BATCH * HID;                 // buf1

    // zero h0^T slab; publish flag=1 after the drain barrier.
    if (tid < 128)
        store_bypass(&hx_sec[(size_t)(k0 + (tid & 7)) * 64 + (bg0 + (tid >> 3))], 0.0f);
    __syncthreads();
    if (tid == 0)
        store_flag(&flags[kslice], 1u);

    // GEMM mapping: 32 K-stripes per reduction, 8x4 tile per half-wave.
    const int kq  = tid & 31;        // 0..31 -> K stripe (= lane in half-wave)
    const int rg  = (tid >> 5) & 7;  // 0..7  -> UNIT rg (4 gate rows)
    const int lbg = tid >> 8;        // 0..1  -> batches lbg*8..+7

    const float4* const C4r = &C4[(lbg * 8) * S4 + kq];
    const float4* const W4r = &W4[(rg * 4) * S4 + kq];

    // Owner lanes: sub 16..23 own batch (sub-16); they hold c and write h.
    const int  sub   = tid & 31;
    const bool owner = (sub >= 16) && (sub < 24);
    const int  ob    = bg0 + lbg * 8 + (sub - 16);   // owner's batch
    const int  ok    = k0 + rg;                      // owner's hidden unit

    const float bb0 = bias_s[rg * 4 + 0];
    const float bb1 = bias_s[rg * 4 + 1];
    const float bb2 = bias_s[rg * 4 + 2];
    const float bb3 = bias_s[rg * 4 + 3];

    float c_reg = 0.0f;
    float h_last = 0.0f;

    for (int t = 0; t < T_STEPS; ++t) {
        const float* h_read  = (t & 1) ? cx_sec : hx_sec;   // h_t^T in buf[t&1]
        float*       h_write = (t & 1) ? hx_sec : cx_sec;   // h_{t+1}^T

        // ---- A2: x-part GEMM (slices 0,1) — x_t staged last step ----
        float acc[8][4];
        #pragma unroll
        for (int i = 0; i < 8; ++i)
            #pragma unroll
            for (int j = 0; j < 4; ++j) acc[i][j] = 0.0f;

        #pragma unroll 1
        for (int it = 0; it < 2; ++it) {
            float4 cv[8], wv[4];
            #pragma unroll
            for (int i = 0; i < 8; ++i) cv[i] = C4r[i * S4 + 32 * it];
            #pragma unroll
            for (int j = 0; j < 4; ++j) wv[j] = W4r[j * S4 + 32 * it];
            #pragma unroll
            for (int i = 0; i < 8; ++i) {
                #pragma unroll
                for (int j = 0; j < 4; ++j) {
                    acc[i][j] = fmaf(cv[i].x, wv[j].x, acc[i][j]);
                    acc[i][j] = fmaf(cv[i].y, wv[j].y, acc[i][j]);
                    acc[i][j] = fmaf(cv[i].z, wv[j].z, acc[i][j]);
                    acc[i][j] = fmaf(cv[i].w, wv[j].w, acc[i][j]);
                }
            }
        }

        // ---- B: wait until all 64 peers published h_t ----
        if (tid < 64) {
            const unsigned target = (unsigned)(t + 1);
            while (!__all((int)(load_flag(&flags[tid]) >= target)))
                __builtin_amdgcn_s_sleep(1);
        }
        __syncthreads();   // full barrier: gather can't hoist above

        // ---- C: gather h_t^T — unit tid's 16 batch values are 64
        //      CONTIGUOUS bytes: 4x dwordx4 bypass loads, one vmcnt.
        //      "=&v": early-clobber so no output aliases the addr pair. ----
        {
            const float* hsrc = h_read + (size_t)tid * 64 + bg0;
            float4 ga, gb, gc, gd;
            asm volatile(
                "global_load_dwordx4 %0, %4, off sc0 sc1\n\t"
                "global_load_dwordx4 %1, %4, off offset:16 sc0 sc1\n\t"
                "global_load_dwordx4 %2, %4, off offset:32 sc0 sc1\n\t"
                "global_load_dwordx4 %3, %4, off offset:48 sc0 sc1\n\t"
                "s_waitcnt vmcnt(0)"
                : "=&v"(ga), "=&v"(gb), "=&v"(gc), "=&v"(gd)
                : "v"(hsrc)
                : "memory");
            float* Cf = (float*)C4;
            Cf[ 0 * (S4 * 4) + 256 + tid] = ga.x;
            Cf[ 1 * (S4 * 4) + 256 + tid] = ga.y;
            Cf[ 2 * (S4 * 4) + 256 + tid] = ga.z;
            Cf[ 3 * (S4 * 4) + 256 + tid] = ga.w;
            Cf[ 4 * (S4 * 4) + 256 + tid] = gb.x;
            Cf[ 5 * (S4 * 4) + 256 + tid] = gb.y;
            Cf[ 6 * (S4 * 4) + 256 + tid] = gb.z;
            Cf[ 7 * (S4 * 4) + 256 + tid] = gb.w;
            Cf[ 8 * (S4 * 4) + 256 + tid] = gc.x;
            Cf[ 9 * (S4 * 4) + 256 + tid] = gc.y;
            Cf[10 * (S4 * 4) + 256 + tid] = gc.z;
            Cf[11 * (S4 * 4) + 256 + tid] = gc.w;
            Cf[12 * (S4 * 4) + 256 + tid] = gd.x;
            Cf[13 * (S4 * 4) + 256 + tid] = gd.y;
            Cf[14 * (S4 * 4) + 256 + tid] = gd.z;
            Cf[15 * (S4 * 4) + 256 + tid] = gd.w;
        }
        __syncthreads();

        // ---- D: h-part GEMM (slices 2..5) ----
        #pragma unroll 1
        for (int it = 2; it < 6; ++it) {
            float4 cv[8], wv[4];
            #pragma unroll
            for (int i = 0; i < 8; ++i) cv[i] = C4r[i * S4 + 32 * it];
            #pragma unroll
            for (int j = 0; j < 4; ++j) wv[j] = W4r[j * S4 + 32 * it];
            #pragma unroll
            for (int i = 0; i < 8; ++i) {
                #pragma unroll
                for (int j = 0; j < 4; ++j) {
                    acc[i][j] = fmaf(cv[i].x, wv[j].x, acc[i][j]);
                    acc[i][j] = fmaf(cv[i].y, wv[j].y, acc[i][j]);
                    acc[i][j] = fmaf(cv[i].z, wv[j].z, acc[i][j]);
                    acc[i][j] = fmaf(cv[i].w, wv[j].w, acc[i][j]);
                }
            }
        }

        // ---- stage x_{t+1} into the C4 x-region (legal: x_t reads were
        //      pre-B; all waves passed the post-C barrier; latency hides
        //      under E's DPP chain). ----
        {
            const int tn = (t + 1 < T_STEPS) ? (t + 1) : t;
            const float4* xs = (const float4*)(x + ((size_t)tn * BATCH + bg0) * DIN);
            #pragma unroll
            for (int m = 0; m < 2; ++m) {
                const int i4 = tid + 512 * m;               // 16b x 64 f4
                C4[(i4 >> 6) * S4 + (i4 & 63)] = xs[i4];
            }
        }

        // ---- E (fused): DPP-reduce; lane 16+i captures batch i's gates ----
        float pf = 0.0f, pi = 0.0f, pg = 0.0f, po = 0.0f;
        #pragma unroll
        for (int i = 0; i < 8; ++i) {
            float g0, g1, g2, g3;
            {
                float v = acc[i][0];
                DPP_ADD(v, 0xB1); DPP_ADD(v, 0x4E);
                DPP_ADD(v, 0x124); DPP_ADD(v, 0x128);
                DPP_ADD(v, 0x142); g0 = v;
            }
            {
                float v = acc[i][1];
                DPP_ADD(v, 0xB1); DPP_ADD(v, 0x4E);
                DPP_ADD(v, 0x124); DPP_ADD(v, 0x128);
                DPP_ADD(v, 0x142); g1 = v;
            }
            {
                float v = acc[i][2];
                DPP_ADD(v, 0xB1); DPP_ADD(v, 0x4E);
                DPP_ADD(v, 0x124); DPP_ADD(v, 0x128);
                DPP_ADD(v, 0x142); g2 = v;
            }
            {
                float v = acc[i][3];
                DPP_ADD(v, 0xB1); DPP_ADD(v, 0x4E);
                DPP_ADD(v, 0x124); DPP_ADD(v, 0x128);
                DPP_ADD(v, 0x142); g3 = v;
            }
            if (sub == 16 + i) { pf = g0; pi = g1; pg = g2; po = g3; }
        }

        // ---- F (in-wave): owners update cell, publish h^T (coalesced:
        //      8 consecutive dwords per half-wave). out[] write deferred
        //      past the flag publish. ----
        if (owner) {
            const float fg = fast_sigmoid(pf + bb0);
            const float ig = fast_sigmoid(pi + bb1);
            const float gg = fast_tanh(pg + bb2);
            const float og = fast_sigmoid(po + bb3);
            c_reg = fg * c_reg + ig * gg;
            h_last = og * fast_tanh(c_reg);
            store_bypass(&h_write[(size_t)ok * 64 + ob], h_last);
        }
        __syncthreads();   // drains vmcnt(0): h^T stores visible; x staged

        // ---- G: publish h_{t+1}; then the off-chain out[] store ----
        if (tid == 0)
            store_flag(&flags[kslice], (unsigned)(t + 2));
        if (owner)
            out[((size_t)t * BATCH + ob) * HID + ok] = h_last;  // drains next barrier
    }

    // ---- DEVICE-WIDE wait: all 4 bgroups x 64 producers at flag >= 513.
    //      Every WG published 513 inside its loop before arriving here and
    //      all 256 WGs are co-resident -> no deadlock. Only after this is
    //      it safe to overwrite the transposed ping-pong region in [b][k]
    //      (the fixup rows alias other bgroups' live h_T columns). ----
    {
        const int wv = tid >> 6;       // wave 0..7
        if (wv < 4) {
            const unsigned target = (unsigned)(T_STEPS + 1);
            const int lane = tid & 63;
            while (!__all((int)(load_flag(&flag_ws[wv * NPROD + lane]) >= target)))
                __builtin_amdgcn_s_sleep(1);
        }
        __syncthreads();
    }
    if (owner) {
        store_bypass(&hx_sec[(size_t)ob * HID + ok], h_last);   // hx = h_512
        store_bypass(&cx_sec[(size_t)ob * HID + ok], c_reg);    // cx = c_512
    }
}

extern "C" void kernel_launch(void* const* d_in, const int* in_sizes, int n_in,
                              void* d_out, int out_size, void* d_ws, size_t ws_size,
                              hipStream_t stream) {
    (void)in_sizes; (void)n_in; (void)ws_size; (void)out_size;
    const float* x  = (const float*)d_in[0];
    const float* Wf = (const float*)d_in[1];
    const float* bf = (const float*)d_in[2];
    const float* Wi = (const float*)d_in[3];
    const float* bi = (const float*)d_in[4];
    const float* Wg = (const float*)d_in[5];
    const float* bg = (const float*)d_in[6];
    const float* Wo = (const float*)d_in[7];
    const float* bo = (const float*)d_in[8];
    float* out = (float*)d_out;
    unsigned* flags = (unsigned*)d_ws;

    // flags[4 bgroups][64 producers], 4B each; must start 0 (d_ws poisoned)
    hipMemsetAsync(d_ws, 0, 4 * NPROD * sizeof(unsigned), stream);

    void* args[] = {&x, &Wf, &bf, &Wi, &bi, &Wg, &bg, &Wo, &bo, &out, &flags};
    hipLaunchCooperativeKernel(reinterpret_cast<void*>(lstm_persistent),
                               dim3(NBLK), dim3(512), args, 0, stream);
}